// Round 4
// baseline (30.838 us; speedup 1.0000x reference)
//
#include <hip/hip_runtime.h>

#define KLD_EPS 1e-6f

// Stage 1: global -> LDS via async global_load_lds (16B/lane, 1 KiB/wave),
// LINEAR LDS dest + inverse-swizzled global SOURCE + swizzled READ (rule:
// both-sides-or-neither; XOR swizzle is an involution so src-perm == read-perm).
// lds4[j] holds row r=j>>3, element k=(j&7)^(r&7). The permutation stays
// within each row's 128-B line, so global coalescing is unchanged.
__global__ __launch_bounds__(256) void gaze_kld_partial(
    const float* __restrict__ pred,
    const float* __restrict__ tru,
    float* __restrict__ partial,
    int B, int nTiles)
{
    __shared__ float4 lds4[2048];   // 32 KiB

    const int t    = threadIdx.x;
    const int lane = t & 63;
    const int wid  = t >> 6;        // wave id 0..3

    const float4* __restrict__ tru4  = (const float4*)tru;   // 8 float4 per row
    const float4* __restrict__ pred4 = (const float4*)pred;  // 1 float4 per row

    float local = 0.0f;
    const long long totF4 = (long long)B * 8;

    for (int tb = blockIdx.x; tb < nTiles; tb += gridDim.x) {
        const long long gBase = (long long)tb * 2048;
        const int row = tb * 256 + t;

        // pred for own row: issue early, independent of staging
        float4 p = make_float4(0.f, 0.f, 1.f, 1.f);
        if (row < B) p = pred4[row];

        if ((tb * 256 + 256) <= B) {
            // full tile: async DMA staging, no VGPR round-trip
            #pragma unroll
            for (int i = 0; i < 8; ++i) {
                int j   = i * 256 + wid * 64 + lane;   // linear LDS float4 idx this lane fills
                int src = (j & ~7) | ((j & 7) ^ ((j >> 3) & 7));
                __builtin_amdgcn_global_load_lds(
                    (const __attribute__((address_space(1))) void*)(tru4 + gBase + src),
                    (__attribute__((address_space(3))) void*)&lds4[i * 256 + wid * 64],
                    16, 0, 0);
            }
        } else {
            // tail tile (unused when B % 256 == 0): VGPR path, swizzled ds_write
            #pragma unroll
            for (int i = 0; i < 8; ++i) {
                int gl = i * 256 + t;
                long long g = gBase + gl;
                float4 v = make_float4(0.f, 0.f, 0.f, 0.f);
                if (g < totF4) v = tru4[g];
                int r = gl >> 3, k = gl & 7;
                lds4[r * 8 + (k ^ (r & 7))] = v;
            }
        }

        __syncthreads();   // drains vmcnt (global_load_lds) + lgkmcnt

        // per-thread row read, conflict-free via XOR offset
        float sx = 0.f, sy = 0.f, sxx = 0.f, syy = 0.f;
        #pragma unroll
        for (int k = 0; k < 8; ++k) {
            float4 v = lds4[t * 8 + (k ^ (t & 7))];
            sx  += v.x + v.z;
            sy  += v.y + v.w;
            sxx += v.x * v.x + v.z * v.z;
            syy += v.y * v.y + v.w * v.w;
        }

        __syncthreads();   // reads done before next iteration overwrites

        if (row < B) {
            float pmx = p.x, pmy = p.y;
            float pvx = p.z + KLD_EPS, pvy = p.w + KLD_EPS;

            float tmx = sx * (1.0f / 16.0f);
            float tmy = sy * (1.0f / 16.0f);
            float tvx = (sxx - 16.0f * tmx * tmx) * (1.0f / 15.0f) + KLD_EPS;
            float tvy = (syy - 16.0f * tmy * tmy) * (1.0f / 15.0f) + KLD_EPS;

            float dx = pmx - tmx, dy = pmy - tmy;
            local += 0.5f * ( __logf(pvx / tvx) + tvx / pvx + dx * dx / pvx
                            + __logf(pvy / tvy) + tvy / pvy + dy * dy / pvy
                            - 2.0f );
        }
    }

    // deterministic block reduction
    __shared__ float sm[4];
    #pragma unroll
    for (int off = 32; off > 0; off >>= 1)
        local += __shfl_down(local, off);
    if ((t & 63) == 0) sm[t >> 6] = local;
    __syncthreads();
    if (t == 0)
        partial[blockIdx.x] = (sm[0] + sm[1]) + (sm[2] + sm[3]);
}

// Stage 2: single block sums per-block partials in fixed order, scales by 1/B.
__global__ __launch_bounds__(256) void gaze_kld_final(
    const float* __restrict__ partial, int n,
    float* __restrict__ out, float invB)
{
    const int t = threadIdx.x;
    float s = 0.0f;
    for (int i = t; i < n; i += blockDim.x) s += partial[i];

    __shared__ float sm[4];
    #pragma unroll
    for (int off = 32; off > 0; off >>= 1)
        s += __shfl_down(s, off);
    if ((t & 63) == 0) sm[t >> 6] = s;
    __syncthreads();
    if (t == 0)
        out[0] = ((sm[0] + sm[1]) + (sm[2] + sm[3])) * invB;
}

extern "C" void kernel_launch(void* const* d_in, const int* in_sizes, int n_in,
                              void* d_out, int out_size, void* d_ws, size_t ws_size,
                              hipStream_t stream) {
    const float* pred = (const float*)d_in[0];
    const float* tru  = (const float*)d_in[1];
    float* out = (float*)d_out;

    const int B = in_sizes[0] / 4;         // pred is (B,4)
    const int nTiles = (B + 255) / 256;

    int blocks = 1024;                     // 4 blocks/CU co-resident (32 KiB LDS each)
    if (blocks > nTiles) blocks = nTiles;
    size_t maxBlocks = ws_size / sizeof(float);
    if ((size_t)blocks > maxBlocks) blocks = (int)maxBlocks;
    if (blocks < 1) blocks = 1;

    float* partials = (float*)d_ws;

    gaze_kld_partial<<<blocks, 256, 0, stream>>>(pred, tru, partials, B, nTiles);
    gaze_kld_final<<<1, 256, 0, stream>>>(partials, blocks, out, 1.0f / (float)B);
}